// Round 1
// baseline (26.596 us; speedup 1.0000x reference)
//
#include <hip/hip_runtime.h>
#include <math.h>

#define K_SIZE 11
#define HALF 5
#define BLOCK 256
#define EPT 8            // outputs per thread
#define TILE (BLOCK*EPT) // 2048 outputs per block

__global__ __launch_bounds__(BLOCK) void dilation1d_kernel(
    const float* __restrict__ in, const float* __restrict__ scale_p,
    float* __restrict__ out, int N)
{
    const float inv4s = 1.0f / (4.0f * scale_p[0]);

    const int t = threadIdx.x;
    const int g0 = blockIdx.x * TILE;
    const int base = g0 + t * EPT;       // first output index for this thread
    const int lbase = base - 8;          // first loaded input index (16B aligned)

    // r[j] = in[base - 8 + j], j = 0..23 ; need j = u+k+3 for u<8, k<11 -> 3..20
    float r[24];
    const bool interior = (blockIdx.x != 0) && (blockIdx.x != gridDim.x - 1);
    if (interior) {
        const float4* p = (const float4*)(in + lbase);
        #pragma unroll
        for (int v = 0; v < 6; ++v) {
            float4 f = p[v];
            r[v*4+0] = f.x; r[v*4+1] = f.y; r[v*4+2] = f.z; r[v*4+3] = f.w;
        }
    } else {
        #pragma unroll
        for (int j = 0; j < 24; ++j) {
            int idx = lbase + j;
            r[j] = (idx >= 0 && idx < N) ? in[idx] : -INFINITY;
        }
    }

    // out[base+u] = max_k ( in[base+u+k-5] + h[k] ),  h[k] = -(k-5)^2/(4*scale)
    float o[EPT];
    #pragma unroll
    for (int u = 0; u < EPT; ++u) {
        float m = -INFINITY;
        #pragma unroll
        for (int k = 0; k < K_SIZE; ++k) {
            const float zk = (float)(k - HALF);
            const float h = -(zk * zk) * inv4s;
            m = fmaxf(m, r[u + k + 3] + h);
        }
        o[u] = m;
    }

    float4* po = (float4*)(out + base);
    po[0] = make_float4(o[0], o[1], o[2], o[3]);
    po[1] = make_float4(o[4], o[5], o[6], o[7]);
}

extern "C" void kernel_launch(void* const* d_in, const int* in_sizes, int n_in,
                              void* d_out, int out_size, void* d_ws, size_t ws_size,
                              hipStream_t stream) {
    const float* in      = (const float*)d_in[0];
    const float* scale_p = (const float*)d_in[1];
    float* out           = (float*)d_out;
    const int N = in_sizes[0];
    const int grid = (N + TILE - 1) / TILE;
    hipLaunchKernelGGL(dilation1d_kernel, dim3(grid), dim3(BLOCK), 0, stream,
                       in, scale_p, out, N);
}